// Round 7
// baseline (134.812 us; speedup 1.0000x reference)
//
#include <hip/hip_runtime.h>

#define NN 20000
#define NE 640000
#define D  128
#define NDPAD 20480
#define CAP 96
#define NPX 2500      // nodes per XCD-range (20000/8)
#define ECHUNK 2000   // edges per chunk; NE/ECHUNK = 320 chunks

using short8 = __attribute__((ext_vector_type(8))) short;
using f32x4  = __attribute__((ext_vector_type(4))) float;
using f32x2  = __attribute__((ext_vector_type(2))) float;

// f32 -> bf16 (RNE) without library types
static __device__ __forceinline__ unsigned short f2bu(float f) {
  unsigned u = __float_as_uint(f);
  unsigned r = (u + 0x7fffu + ((u >> 16) & 1u)) >> 16;
  return (unsigned short)r;
}
static __device__ __forceinline__ unsigned packbf(float a, float b) {
  return (unsigned)f2bu(a) | ((unsigned)f2bu(b) << 16);
}
static __device__ __forceinline__ float bflo(unsigned u) { return __uint_as_float(u << 16); }
static __device__ __forceinline__ float bfhi(unsigned u) { return __uint_as_float(u & 0xffff0000u); }

// ---- fused prep (R8 form + fp8 table) ----
// [0,80): zero fill | [80,2580): x->bf16+fp8 | 2580: zero-rows | [2581,2965): weights
#define ZB_BLK 80
#define CVT_BLK 2500
#define W_BLK 384
#define PREP_BLK (ZB_BLK + CVT_BLK + 1 + W_BLK)

__global__ __launch_bounds__(256) void prep_kernel(
    const float4* __restrict__ x, uint2* __restrict__ zbA, uint2* __restrict__ zbB,
    unsigned* __restrict__ zf8A, unsigned* __restrict__ zf8B,
    const float* __restrict__ wa, const float* __restrict__ wb,
    const float* __restrict__ wc, const float* __restrict__ wd,
    const float* __restrict__ we, const float* __restrict__ wf,
    unsigned short* __restrict__ wt_base,
    int* __restrict__ fill) {
  int b = blockIdx.x;
  int t = threadIdx.x;
  if (b < ZB_BLK) {
    fill[b * 256 + t] = 0;               // covers 20480 exactly
  } else if (b < ZB_BLK + CVT_BLK) {
    int i = (b - ZB_BLK) * 256 + t;      // < 640000 exactly (float4 groups)
    float4 v = x[i];
    zbA[i] = make_uint2(packbf(v.x, v.y), packbf(v.z, v.w));
    unsigned e = __builtin_amdgcn_cvt_pk_fp8_f32(v.x, v.y, 0u, false);
    e = __builtin_amdgcn_cvt_pk_fp8_f32(v.z, v.w, e, true);
    zf8A[i] = e;                         // 4 fp8 bytes = same 4 features
  } else if (b == ZB_BLK + CVT_BLK) {
    if (t < 32)       zbA[NN * 32 + t] = make_uint2(0u, 0u);
    else if (t < 64)  zbB[NN * 32 + (t - 32)] = make_uint2(0u, 0u);
    else if (t < 96)  zf8A[NN * 32 + (t - 64)] = 0u;   // fp8 zero row
    else if (t < 128) zf8B[NN * 32 + (t - 96)] = 0u;
  } else {
    int wb_ = b - (ZB_BLK + CVT_BLK + 1);
    int widx = wb_ >> 6;
    const float* ws[6] = {wa, wb, wc, wd, we, wf};
    const float* w = ws[widx];
    unsigned short* wt = wt_base + (size_t)widx * D * D;
    int idx = (wb_ & 63) * 256 + t;      // 0..16383
    int n = idx >> 7, k = idx & 127;
    wt[idx] = f2bu(w[k * D + n]);
  }
}

// ---- XCD-partitioned ELL scatter (unchanged) ----
__global__ __launch_bounds__(256) void csr_kernel(const int* __restrict__ ei,
                                                  int* __restrict__ fill,
                                                  unsigned short* __restrict__ col_ell) {
  const int xcd = blockIdx.x & 7;
  const int chunk = blockIdx.x >> 3;
  const int nlo = xcd * NPX;
  const int nhi = nlo + NPX;
  const int e0 = chunk * ECHUNK;
  const int4* s4 = reinterpret_cast<const int4*>(ei + e0);
  const int4* d4 = reinterpret_cast<const int4*>(ei + NE + e0);
  for (int q = threadIdx.x; q < ECHUNK / 4; q += 256) {
    int4 d = d4[q];
    int4 s = s4[q];
    if (d.x >= nlo && d.x < nhi) {
      int p = atomicAdd(&fill[d.x], 1);
      if (p < CAP) col_ell[d.x * CAP + p] = (unsigned short)s.x;
    }
    if (d.y >= nlo && d.y < nhi) {
      int p = atomicAdd(&fill[d.y], 1);
      if (p < CAP) col_ell[d.y * CAP + p] = (unsigned short)s.y;
    }
    if (d.z >= nlo && d.z < nhi) {
      int p = atomicAdd(&fill[d.z], 1);
      if (p < CAP) col_ell[d.z * CAP + p] = (unsigned short)s.z;
    }
    if (d.w >= nlo && d.w < nhi) {
      int p = atomicAdd(&fill[d.w], 1);
      if (p < CAP) col_ell[d.w * CAP + p] = (unsigned short)s.w;
    }
  }
}

// ---- fused layer: agg + 2-GEMM MLP. 16 nodes/block, 8 waves. ----
// R16: 8-edges-per-instruction gather. Evidence (R13/R14/R15 timing): agg
// cost ~= instrs x (60 + 6*lines) cy — per-scatter-instruction bound, not
// MSHR/latency/bytes. fp8 row = 128B = 8 lanes x uint4, so one instruction
// now covers 8 edges (was 4): instruction count halves at constant lines.
// Lane geometry: hf8=lane>>3 (edge in chunk of 8), cs8=lane&7 (16B slot).
// Butterfly xor 8/16/32; lanes hf8 0/1 add exact bf16 self rows and write Ht.
__global__ __launch_bounds__(512, 4) void layer_kernel(
    const uint4* __restrict__ zb4,             // bf16 [NN+1][16] (self rows)
    const uint4* __restrict__ zf4,             // fp8  [NN+1][8]  (gather rows)
    const int* __restrict__ deg,
    const unsigned short* __restrict__ col_ell,
    const unsigned short* __restrict__ w1t,    // [n][k] bf16
    const float* __restrict__ b1,
    const unsigned short* __restrict__ w2t,    // [n][k] bf16
    const float* __restrict__ b2,
    unsigned short* __restrict__ zb_out,       // bf16 out (layers 0,1)
    unsigned char* __restrict__ zf_out,        // fp8 out (layers 0,1)
    float* __restrict__ f_out) {               // f32 out (last layer) or null
  __shared__ alignas(16) unsigned char Ht[16 * 256];   // h = z+agg, swizzled bf16
  __shared__ alignas(16) unsigned char H2[16 * 256];   // relu(h@w1+b1), swizzled
  __shared__ alignas(16) unsigned short sCol[16 * CAP]; // staged ELL lists (3KB)
  __shared__ int sDeg[16];
  const int lane = threadIdx.x & 63;
  const int wv = threadIdx.x >> 6;             // 0..7
  const int nb = blockIdx.x * 16;

  // ---- stage block's ELL lists + degrees into LDS (coalesced) ----
  {
    const uint4* src = reinterpret_cast<const uint4*>(col_ell + (size_t)nb * CAP);
    uint4* dst = reinterpret_cast<uint4*>(sCol);
    if (threadIdx.x < 16 * CAP * 2 / 16) dst[threadIdx.x] = src[threadIdx.x];  // 192 uint4
    if (threadIdx.x < 16) sDeg[threadIdx.x] = deg[nb + threadIdx.x];
  }
  __syncthreads();

  // ---- aggregation: wave wv owns rows {2wv, 2wv+1} ----
  {
    const int hf8 = lane >> 3;     // edge within a chunk of 8
    const int cs8 = lane & 7;      // 16B slot within the 128B fp8 row
    const int r0 = wv * 2, r1 = r0 + 1;
    const int nodeA = __builtin_amdgcn_readfirstlane(nb + r0);
    const int nodeB = __builtin_amdgcn_readfirstlane(nb + r1);
    const int dgA = sDeg[r0], dgB = sDeg[r1];
    const unsigned short* cbA = sCol + r0 * CAP;
    const unsigned short* cbB = sCol + r1 * CAP;
    const int nch = __builtin_amdgcn_readfirstlane((max(dgA, dgB) + 7) >> 3);
    // exact bf16 self row halves (lanes hf8==0 use nodeA's, hf8==1 nodeB's)
    const int selfNode = (hf8 & 1) ? nodeB : nodeA;
    uint4 sLo = zb4[(size_t)selfNode * 16 + cs8 * 2];
    uint4 sHi = zb4[(size_t)selfNode * 16 + cs8 * 2 + 1];

    float a[16], cc[16];
#pragma unroll
    for (int j = 0; j < 16; ++j) { a[j] = 0.f; cc[j] = 0.f; }

#pragma unroll 2
    for (int c = 0; c < nch; ++c) {
      int slot = c * 8 + hf8;
      int idxA = (slot < dgA) ? (int)cbA[slot] : NN;
      int idxB = (slot < dgB) ? (int)cbB[slot] : NN;
      uint4 u = zf4[(size_t)idxA * 8 + cs8];
      uint4 v = zf4[(size_t)idxB * 8 + cs8];
      f32x2 p;
      p = __builtin_amdgcn_cvt_pk_f32_fp8(u.x, false); a[0] += p.x;  a[1] += p.y;
      p = __builtin_amdgcn_cvt_pk_f32_fp8(u.x, true);  a[2] += p.x;  a[3] += p.y;
      p = __builtin_amdgcn_cvt_pk_f32_fp8(u.y, false); a[4] += p.x;  a[5] += p.y;
      p = __builtin_amdgcn_cvt_pk_f32_fp8(u.y, true);  a[6] += p.x;  a[7] += p.y;
      p = __builtin_amdgcn_cvt_pk_f32_fp8(u.z, false); a[8] += p.x;  a[9] += p.y;
      p = __builtin_amdgcn_cvt_pk_f32_fp8(u.z, true);  a[10] += p.x; a[11] += p.y;
      p = __builtin_amdgcn_cvt_pk_f32_fp8(u.w, false); a[12] += p.x; a[13] += p.y;
      p = __builtin_amdgcn_cvt_pk_f32_fp8(u.w, true);  a[14] += p.x; a[15] += p.y;
      p = __builtin_amdgcn_cvt_pk_f32_fp8(v.x, false); cc[0] += p.x;  cc[1] += p.y;
      p = __builtin_amdgcn_cvt_pk_f32_fp8(v.x, true);  cc[2] += p.x;  cc[3] += p.y;
      p = __builtin_amdgcn_cvt_pk_f32_fp8(v.y, false); cc[4] += p.x;  cc[5] += p.y;
      p = __builtin_amdgcn_cvt_pk_f32_fp8(v.y, true);  cc[6] += p.x;  cc[7] += p.y;
      p = __builtin_amdgcn_cvt_pk_f32_fp8(v.z, false); cc[8] += p.x;  cc[9] += p.y;
      p = __builtin_amdgcn_cvt_pk_f32_fp8(v.z, true);  cc[10] += p.x; cc[11] += p.y;
      p = __builtin_amdgcn_cvt_pk_f32_fp8(v.w, false); cc[12] += p.x; cc[13] += p.y;
      p = __builtin_amdgcn_cvt_pk_f32_fp8(v.w, true);  cc[14] += p.x; cc[15] += p.y;
    }
    // butterfly over the 8 hf8 groups: lanes differing in bits 3/4/5 share cs8
#pragma unroll
    for (int j = 0; j < 16; ++j) { a[j] += __shfl_xor(a[j], 8);  cc[j] += __shfl_xor(cc[j], 8); }
#pragma unroll
    for (int j = 0; j < 16; ++j) { a[j] += __shfl_xor(a[j], 16); cc[j] += __shfl_xor(cc[j], 16); }
#pragma unroll
    for (int j = 0; j < 16; ++j) { a[j] += __shfl_xor(a[j], 32); cc[j] += __shfl_xor(cc[j], 32); }

    if (hf8 == 0) {
      float t0 = a[0] + bflo(sLo.x),  t1 = a[1] + bfhi(sLo.x);
      float t2 = a[2] + bflo(sLo.y),  t3 = a[3] + bfhi(sLo.y);
      float t4 = a[4] + bflo(sLo.z),  t5 = a[5] + bfhi(sLo.z);
      float t6 = a[6] + bflo(sLo.w),  t7 = a[7] + bfhi(sLo.w);
      float t8 = a[8] + bflo(sHi.x),  t9 = a[9] + bfhi(sHi.x);
      float t10 = a[10] + bflo(sHi.y), t11 = a[11] + bfhi(sHi.y);
      float t12 = a[12] + bflo(sHi.z), t13 = a[13] + bfhi(sHi.z);
      float t14 = a[14] + bflo(sHi.w), t15 = a[15] + bfhi(sHi.w);
      uint4 pLo, pHi;
      pLo.x = packbf(t0, t1);   pLo.y = packbf(t2, t3);
      pLo.z = packbf(t4, t5);   pLo.w = packbf(t6, t7);
      pHi.x = packbf(t8, t9);   pHi.y = packbf(t10, t11);
      pHi.z = packbf(t12, t13); pHi.w = packbf(t14, t15);
      int base = r0 * 256 + cs8 * 32;
      *reinterpret_cast<uint4*>(&Ht[(base) ^ ((r0 & 7) << 4)]) = pLo;
      *reinterpret_cast<uint4*>(&Ht[(base + 16) ^ ((r0 & 7) << 4)]) = pHi;
    } else if (hf8 == 1) {
      float t0 = cc[0] + bflo(sLo.x),  t1 = cc[1] + bfhi(sLo.x);
      float t2 = cc[2] + bflo(sLo.y),  t3 = cc[3] + bfhi(sLo.y);
      float t4 = cc[4] + bflo(sLo.z),  t5 = cc[5] + bfhi(sLo.z);
      float t6 = cc[6] + bflo(sLo.w),  t7 = cc[7] + bfhi(sLo.w);
      float t8 = cc[8] + bflo(sHi.x),  t9 = cc[9] + bfhi(sHi.x);
      float t10 = cc[10] + bflo(sHi.y), t11 = cc[11] + bfhi(sHi.y);
      float t12 = cc[12] + bflo(sHi.z), t13 = cc[13] + bfhi(sHi.z);
      float t14 = cc[14] + bflo(sHi.w), t15 = cc[15] + bfhi(sHi.w);
      uint4 pLo, pHi;
      pLo.x = packbf(t0, t1);   pLo.y = packbf(t2, t3);
      pLo.z = packbf(t4, t5);   pLo.w = packbf(t6, t7);
      pHi.x = packbf(t8, t9);   pHi.y = packbf(t10, t11);
      pHi.z = packbf(t12, t13); pHi.w = packbf(t14, t15);
      int base = r1 * 256 + cs8 * 32;
      *reinterpret_cast<uint4*>(&Ht[(base) ^ ((r1 & 7) << 4)]) = pLo;
      *reinterpret_cast<uint4*>(&Ht[(base + 16) ^ ((r1 & 7) << 4)]) = pHi;
    }
  }
  __syncthreads();

  const int ar = lane & 15;        // A row / B col / C col
  const int kg = lane >> 4;        // k-group 0..3
  const int crb = kg * 4;          // C/D row base

  // ---- GEMM1: wave's N-tile nt = wv ----
  short8 a[4];
#pragma unroll
  for (int ks = 0; ks < 4; ++ks) {
    int byte = (ar * 256 + (ks * 32 + kg * 8) * 2) ^ ((ar & 7) << 4);
    a[ks] = *reinterpret_cast<const short8*>(&Ht[byte]);
  }
  f32x4 acc = (f32x4){0.f, 0.f, 0.f, 0.f};
#pragma unroll
  for (int ks = 0; ks < 4; ++ks) {
    short8 b = *reinterpret_cast<const short8*>(&w1t[(wv * 16 + ar) * D + ks * 32 + kg * 8]);
    acc = __builtin_amdgcn_mfma_f32_16x16x32_bf16(a[ks], b, acc, 0, 0, 0);
  }
  {
    int col = wv * 16 + ar;
    float bias = b1[col];
#pragma unroll
    for (int j = 0; j < 4; ++j) {
      int r = crb + j;
      float v = fmaxf(acc[j] + bias, 0.f);
      int byte = (r * 256 + col * 2) ^ ((r & 7) << 4);
      *reinterpret_cast<unsigned short*>(&H2[byte]) = f2bu(v);
    }
  }
  __syncthreads();

  // ---- GEMM2 ----
  short8 a2[4];
#pragma unroll
  for (int ks = 0; ks < 4; ++ks) {
    int byte = (ar * 256 + (ks * 32 + kg * 8) * 2) ^ ((ar & 7) << 4);
    a2[ks] = *reinterpret_cast<const short8*>(&H2[byte]);
  }
  acc = (f32x4){0.f, 0.f, 0.f, 0.f};
#pragma unroll
  for (int ks = 0; ks < 4; ++ks) {
    short8 b = *reinterpret_cast<const short8*>(&w2t[(wv * 16 + ar) * D + ks * 32 + kg * 8]);
    acc = __builtin_amdgcn_mfma_f32_16x16x32_bf16(a2[ks], b, acc, 0, 0, 0);
  }
  {
    int col = wv * 16 + ar;
    float bias = b2[col];
    if (f_out != nullptr) {
#pragma unroll
      for (int j = 0; j < 4; ++j) {
        int row = nb + crb + j;
        f_out[(size_t)row * D + col] = fmaxf(acc[j] + bias, 0.f);
      }
    } else {
#pragma unroll
      for (int j = 0; j < 4; ++j) {
        int row = nb + crb + j;
        float v = fmaxf(acc[j] + bias, 0.f);
        zb_out[(size_t)row * D + col] = f2bu(v);
        unsigned e = __builtin_amdgcn_cvt_pk_fp8_f32(v, v, 0u, false);
        zf_out[(size_t)row * D + col] = (unsigned char)(e & 0xffu);
      }
    }
  }
}

extern "C" void kernel_launch(void* const* d_in, const int* in_sizes, int n_in,
                              void* d_out, int out_size, void* d_ws, size_t ws_size,
                              hipStream_t stream) {
  const float* x = (const float*)d_in[0];
  const int* ei = (const int*)d_in[1];
  const float* w1[3] = {(const float*)d_in[2], (const float*)d_in[6], (const float*)d_in[10]};
  const float* b1[3] = {(const float*)d_in[3], (const float*)d_in[7], (const float*)d_in[11]};
  const float* w2[3] = {(const float*)d_in[4], (const float*)d_in[8], (const float*)d_in[12]};
  const float* b2[3] = {(const float*)d_in[5], (const float*)d_in[9], (const float*)d_in[13]};
  float* out = (float*)d_out;

  char* wsb = (char*)d_ws;
  size_t off = 0;
  auto alloc = [&](size_t bytes) -> void* {
    void* p = wsb + off;
    off += (bytes + 255) & ~(size_t)255;
    return p;
  };
  unsigned short* zbA = (unsigned short*)alloc((size_t)(NN + 1) * D * 2);
  unsigned short* zbB = (unsigned short*)alloc((size_t)(NN + 1) * D * 2);
  unsigned char* zfA = (unsigned char*)alloc((size_t)(NN + 1) * D);
  unsigned char* zfB = (unsigned char*)alloc((size_t)(NN + 1) * D);
  unsigned short* wt  = (unsigned short*)alloc((size_t)6 * D * D * 2);
  int* fill = (int*)alloc((size_t)NDPAD * 4);
  unsigned short* col_ell = (unsigned short*)alloc((size_t)NDPAD * CAP * 2);

  prep_kernel<<<PREP_BLK, 256, 0, stream>>>(
      (const float4*)x, (uint2*)zbA, (uint2*)zbB, (unsigned*)zfA, (unsigned*)zfB,
      w1[0], w2[0], w1[1], w2[1], w1[2], w2[2], wt, fill);
  csr_kernel<<<(NE / ECHUNK) * 8, 256, 0, stream>>>(ei, fill, col_ell);

  const unsigned short* zin = zbA;
  unsigned short* zout = zbB;
  const unsigned char* fin = zfA;
  unsigned char* fout = zfB;
  for (int l = 0; l < 3; ++l) {
    layer_kernel<<<NN / 16, 512, 0, stream>>>(
        (const uint4*)zin, (const uint4*)fin, fill, col_ell,
        wt + (size_t)(2 * l) * D * D, b1[l],
        wt + (size_t)(2 * l + 1) * D * D, b2[l],
        zout, fout, (l == 2) ? out : nullptr);
    const unsigned short* t = zin; zin = zout; zout = (unsigned short*)t;
    const unsigned char* t2 = fin; fin = fout; fout = (unsigned char*)t2;
  }
}

// Round 8
// 125.332 us; speedup vs baseline: 1.0756x; 1.0756x over previous
//
#include <hip/hip_runtime.h>

#define NN 20000
#define NE 640000
#define D  128
#define NDPAD 20480
#define CAP 96
#define NPX 2500      // nodes per XCD-range (20000/8)
#define ECHUNK 2000   // edges per chunk; NE/ECHUNK = 320 chunks

using short8 = __attribute__((ext_vector_type(8))) short;
using f32x4  = __attribute__((ext_vector_type(4))) float;
using f32x2  = __attribute__((ext_vector_type(2))) float;

// f32 -> bf16 (RNE) without library types
static __device__ __forceinline__ unsigned short f2bu(float f) {
  unsigned u = __float_as_uint(f);
  unsigned r = (u + 0x7fffu + ((u >> 16) & 1u)) >> 16;
  return (unsigned short)r;
}
static __device__ __forceinline__ unsigned packbf(float a, float b) {
  return (unsigned)f2bu(a) | ((unsigned)f2bu(b) << 16);
}
static __device__ __forceinline__ float bflo(unsigned u) { return __uint_as_float(u << 16); }
static __device__ __forceinline__ float bfhi(unsigned u) { return __uint_as_float(u & 0xffff0000u); }

// ---- fused prep (R8 form + fp8 table) ----
// [0,80): zero fill | [80,2580): x->bf16+fp8 | 2580: zero-rows | [2581,2965): weights
#define ZB_BLK 80
#define CVT_BLK 2500
#define W_BLK 384
#define PREP_BLK (ZB_BLK + CVT_BLK + 1 + W_BLK)

__global__ __launch_bounds__(256) void prep_kernel(
    const float4* __restrict__ x, uint2* __restrict__ zbA, uint2* __restrict__ zbB,
    unsigned* __restrict__ zf8A, unsigned* __restrict__ zf8B,
    const float* __restrict__ wa, const float* __restrict__ wb,
    const float* __restrict__ wc, const float* __restrict__ wd,
    const float* __restrict__ we, const float* __restrict__ wf,
    unsigned short* __restrict__ wt_base,
    int* __restrict__ fill) {
  int b = blockIdx.x;
  int t = threadIdx.x;
  if (b < ZB_BLK) {
    fill[b * 256 + t] = 0;               // covers 20480 exactly
  } else if (b < ZB_BLK + CVT_BLK) {
    int i = (b - ZB_BLK) * 256 + t;      // < 640000 exactly (float4 groups)
    float4 v = x[i];
    zbA[i] = make_uint2(packbf(v.x, v.y), packbf(v.z, v.w));
    unsigned e = __builtin_amdgcn_cvt_pk_fp8_f32(v.x, v.y, 0u, false);
    e = __builtin_amdgcn_cvt_pk_fp8_f32(v.z, v.w, e, true);
    zf8A[i] = e;                         // 4 fp8 bytes = same 4 features
  } else if (b == ZB_BLK + CVT_BLK) {
    if (t < 32)       zbA[NN * 32 + t] = make_uint2(0u, 0u);
    else if (t < 64)  zbB[NN * 32 + (t - 32)] = make_uint2(0u, 0u);
    else if (t < 96)  zf8A[NN * 32 + (t - 64)] = 0u;   // fp8 zero row
    else if (t < 128) zf8B[NN * 32 + (t - 96)] = 0u;
  } else {
    int wb_ = b - (ZB_BLK + CVT_BLK + 1);
    int widx = wb_ >> 6;
    const float* ws[6] = {wa, wb, wc, wd, we, wf};
    const float* w = ws[widx];
    unsigned short* wt = wt_base + (size_t)widx * D * D;
    int idx = (wb_ & 63) * 256 + t;      // 0..16383
    int n = idx >> 7, k = idx & 127;
    wt[idx] = f2bu(w[k * D + n]);
  }
}

// ---- XCD-partitioned ELL scatter (unchanged) ----
__global__ __launch_bounds__(256) void csr_kernel(const int* __restrict__ ei,
                                                  int* __restrict__ fill,
                                                  unsigned short* __restrict__ col_ell) {
  const int xcd = blockIdx.x & 7;
  const int chunk = blockIdx.x >> 3;
  const int nlo = xcd * NPX;
  const int nhi = nlo + NPX;
  const int e0 = chunk * ECHUNK;
  const int4* s4 = reinterpret_cast<const int4*>(ei + e0);
  const int4* d4 = reinterpret_cast<const int4*>(ei + NE + e0);
  for (int q = threadIdx.x; q < ECHUNK / 4; q += 256) {
    int4 d = d4[q];
    int4 s = s4[q];
    if (d.x >= nlo && d.x < nhi) {
      int p = atomicAdd(&fill[d.x], 1);
      if (p < CAP) col_ell[d.x * CAP + p] = (unsigned short)s.x;
    }
    if (d.y >= nlo && d.y < nhi) {
      int p = atomicAdd(&fill[d.y], 1);
      if (p < CAP) col_ell[d.y * CAP + p] = (unsigned short)s.y;
    }
    if (d.z >= nlo && d.z < nhi) {
      int p = atomicAdd(&fill[d.z], 1);
      if (p < CAP) col_ell[d.z * CAP + p] = (unsigned short)s.z;
    }
    if (d.w >= nlo && d.w < nhi) {
      int p = atomicAdd(&fill[d.w], 1);
      if (p < CAP) col_ell[d.w * CAP + p] = (unsigned short)s.w;
    }
  }
}

// ---- fused layer: agg + 2-GEMM MLP. 16 nodes/block, 8 waves. ----
// R17: per-node sequential gather loops (A then B), eliminating the
// max(dgA,dgB) zero-row padding clusters (~9% of all gathers). Evidence
// (R13-R16 cross-compare): agg cost ~= 25cy per discontiguous address-
// cluster per CU, invariant to instr count/bytes/latency — so the only
// lever is cluster count. Per-node geometry identical to R15 (4 edges x
// 16 uint2 slots), so per-feature add order is bit-identical -> absmax
// must stay 1.125.
__global__ __launch_bounds__(512, 4) void layer_kernel(
    const uint4* __restrict__ zb4,             // bf16 [NN+1][16] (self rows)
    const uint2* __restrict__ zf2,             // fp8  [NN+1][16] (gather rows)
    const int* __restrict__ deg,
    const unsigned short* __restrict__ col_ell,
    const unsigned short* __restrict__ w1t,    // [n][k] bf16
    const float* __restrict__ b1,
    const unsigned short* __restrict__ w2t,    // [n][k] bf16
    const float* __restrict__ b2,
    unsigned short* __restrict__ zb_out,       // bf16 out (layers 0,1)
    unsigned char* __restrict__ zf_out,        // fp8 out (layers 0,1)
    float* __restrict__ f_out) {               // f32 out (last layer) or null
  __shared__ alignas(16) unsigned char Ht[16 * 256];   // h = z+agg, swizzled bf16
  __shared__ alignas(16) unsigned char H2[16 * 256];   // relu(h@w1+b1), swizzled
  __shared__ alignas(16) unsigned short sCol[16 * CAP]; // staged ELL lists (3KB)
  __shared__ int sDeg[16];
  const int lane = threadIdx.x & 63;
  const int wv = threadIdx.x >> 6;             // 0..7
  const int nb = blockIdx.x * 16;
  const int hf = lane >> 4;        // which edge within a 4-edge chunk
  const int cs = lane & 15;        // 8B fp8 slot / 16B bf16 slot within a row

  // ---- stage block's ELL lists + degrees into LDS (coalesced) ----
  {
    const uint4* src = reinterpret_cast<const uint4*>(col_ell + (size_t)nb * CAP);
    uint4* dst = reinterpret_cast<uint4*>(sCol);
    if (threadIdx.x < 16 * CAP * 2 / 16) dst[threadIdx.x] = src[threadIdx.x];  // 192 uint4
    if (threadIdx.x < 16) sDeg[threadIdx.x] = deg[nb + threadIdx.x];
  }
  __syncthreads();

  // ---- aggregation: wave wv owns rows {2wv, 2wv+1}, processed sequentially ----
  {
    const int r0 = wv * 2, r1 = r0 + 1;
    const int nodeA = __builtin_amdgcn_readfirstlane(nb + r0);
    const int nodeB = __builtin_amdgcn_readfirstlane(nb + r1);
    const int dgA = sDeg[r0], dgB = sDeg[r1];
    const unsigned short* cbA = sCol + r0 * CAP;
    const unsigned short* cbB = sCol + r1 * CAP;
    const int nchA = __builtin_amdgcn_readfirstlane((dgA + 3) >> 2);
    const int nchB = __builtin_amdgcn_readfirstlane((dgB + 3) >> 2);
    // self rows (bf16, exact): in flight during the fp8 gathers
    uint4 sA = zb4[(size_t)nodeA * 16 + cs];
    uint4 sB = zb4[(size_t)nodeB * 16 + cs];

    float a0 = 0.f, a1 = 0.f, a2 = 0.f, a3 = 0.f;
    float a4 = 0.f, a5 = 0.f, a6 = 0.f, a7 = 0.f;
    // ---- node A ----
#pragma unroll 8
    for (int c = 0; c < nchA; ++c) {
      int slot = c * 4 + hf;
      int idxA = (slot < dgA) ? (int)cbA[slot] : NN;
      uint2 u = zf2[(size_t)idxA * 16 + cs];
      f32x2 p;
      p = __builtin_amdgcn_cvt_pk_f32_fp8(u.x, false); a0 += p.x; a1 += p.y;
      p = __builtin_amdgcn_cvt_pk_f32_fp8(u.x, true);  a2 += p.x; a3 += p.y;
      p = __builtin_amdgcn_cvt_pk_f32_fp8(u.y, false); a4 += p.x; a5 += p.y;
      p = __builtin_amdgcn_cvt_pk_f32_fp8(u.y, true);  a6 += p.x; a7 += p.y;
    }
    a0 += __shfl_xor(a0, 16); a1 += __shfl_xor(a1, 16);
    a2 += __shfl_xor(a2, 16); a3 += __shfl_xor(a3, 16);
    a4 += __shfl_xor(a4, 16); a5 += __shfl_xor(a5, 16);
    a6 += __shfl_xor(a6, 16); a7 += __shfl_xor(a7, 16);
    a0 += __shfl_xor(a0, 32); a1 += __shfl_xor(a1, 32);
    a2 += __shfl_xor(a2, 32); a3 += __shfl_xor(a3, 32);
    a4 += __shfl_xor(a4, 32); a5 += __shfl_xor(a5, 32);
    a6 += __shfl_xor(a6, 32); a7 += __shfl_xor(a7, 32);
    a0 += bflo(sA.x); a1 += bfhi(sA.x);
    a2 += bflo(sA.y); a3 += bfhi(sA.y);
    a4 += bflo(sA.z); a5 += bfhi(sA.z);
    a6 += bflo(sA.w); a7 += bfhi(sA.w);
    if (hf == 0) {
      uint4 p;
      p.x = packbf(a0, a1); p.y = packbf(a2, a3);
      p.z = packbf(a4, a5); p.w = packbf(a6, a7);
      *reinterpret_cast<uint4*>(&Ht[(r0 * 256 + cs * 16) ^ ((r0 & 7) << 4)]) = p;
    }
    // ---- node B (reuse accumulator bank) ----
    a0 = 0.f; a1 = 0.f; a2 = 0.f; a3 = 0.f;
    a4 = 0.f; a5 = 0.f; a6 = 0.f; a7 = 0.f;
#pragma unroll 8
    for (int c = 0; c < nchB; ++c) {
      int slot = c * 4 + hf;
      int idxB = (slot < dgB) ? (int)cbB[slot] : NN;
      uint2 v = zf2[(size_t)idxB * 16 + cs];
      f32x2 p;
      p = __builtin_amdgcn_cvt_pk_f32_fp8(v.x, false); a0 += p.x; a1 += p.y;
      p = __builtin_amdgcn_cvt_pk_f32_fp8(v.x, true);  a2 += p.x; a3 += p.y;
      p = __builtin_amdgcn_cvt_pk_f32_fp8(v.y, false); a4 += p.x; a5 += p.y;
      p = __builtin_amdgcn_cvt_pk_f32_fp8(v.y, true);  a6 += p.x; a7 += p.y;
    }
    a0 += __shfl_xor(a0, 16); a1 += __shfl_xor(a1, 16);
    a2 += __shfl_xor(a2, 16); a3 += __shfl_xor(a3, 16);
    a4 += __shfl_xor(a4, 16); a5 += __shfl_xor(a5, 16);
    a6 += __shfl_xor(a6, 16); a7 += __shfl_xor(a7, 16);
    a0 += __shfl_xor(a0, 32); a1 += __shfl_xor(a1, 32);
    a2 += __shfl_xor(a2, 32); a3 += __shfl_xor(a3, 32);
    a4 += __shfl_xor(a4, 32); a5 += __shfl_xor(a5, 32);
    a6 += __shfl_xor(a6, 32); a7 += __shfl_xor(a7, 32);
    a0 += bflo(sB.x); a1 += bfhi(sB.x);
    a2 += bflo(sB.y); a3 += bfhi(sB.y);
    a4 += bflo(sB.z); a5 += bfhi(sB.z);
    a6 += bflo(sB.w); a7 += bfhi(sB.w);
    if (hf == 0) {
      uint4 p;
      p.x = packbf(a0, a1); p.y = packbf(a2, a3);
      p.z = packbf(a4, a5); p.w = packbf(a6, a7);
      *reinterpret_cast<uint4*>(&Ht[(r1 * 256 + cs * 16) ^ ((r1 & 7) << 4)]) = p;
    }
  }
  __syncthreads();

  const int ar = lane & 15;        // A row / B col / C col
  const int kg = lane >> 4;        // k-group 0..3
  const int crb = kg * 4;          // C/D row base

  // ---- GEMM1: wave's N-tile nt = wv ----
  short8 a[4];
#pragma unroll
  for (int ks = 0; ks < 4; ++ks) {
    int byte = (ar * 256 + (ks * 32 + kg * 8) * 2) ^ ((ar & 7) << 4);
    a[ks] = *reinterpret_cast<const short8*>(&Ht[byte]);
  }
  f32x4 acc = (f32x4){0.f, 0.f, 0.f, 0.f};
#pragma unroll
  for (int ks = 0; ks < 4; ++ks) {
    short8 b = *reinterpret_cast<const short8*>(&w1t[(wv * 16 + ar) * D + ks * 32 + kg * 8]);
    acc = __builtin_amdgcn_mfma_f32_16x16x32_bf16(a[ks], b, acc, 0, 0, 0);
  }
  {
    int col = wv * 16 + ar;
    float bias = b1[col];
#pragma unroll
    for (int j = 0; j < 4; ++j) {
      int r = crb + j;
      float v = fmaxf(acc[j] + bias, 0.f);
      int byte = (r * 256 + col * 2) ^ ((r & 7) << 4);
      *reinterpret_cast<unsigned short*>(&H2[byte]) = f2bu(v);
    }
  }
  __syncthreads();

  // ---- GEMM2 ----
  short8 a2[4];
#pragma unroll
  for (int ks = 0; ks < 4; ++ks) {
    int byte = (ar * 256 + (ks * 32 + kg * 8) * 2) ^ ((ar & 7) << 4);
    a2[ks] = *reinterpret_cast<const short8*>(&H2[byte]);
  }
  acc = (f32x4){0.f, 0.f, 0.f, 0.f};
#pragma unroll
  for (int ks = 0; ks < 4; ++ks) {
    short8 b = *reinterpret_cast<const short8*>(&w2t[(wv * 16 + ar) * D + ks * 32 + kg * 8]);
    acc = __builtin_amdgcn_mfma_f32_16x16x32_bf16(a2[ks], b, acc, 0, 0, 0);
  }
  {
    int col = wv * 16 + ar;
    float bias = b2[col];
    if (f_out != nullptr) {
#pragma unroll
      for (int j = 0; j < 4; ++j) {
        int row = nb + crb + j;
        f_out[(size_t)row * D + col] = fmaxf(acc[j] + bias, 0.f);
      }
    } else {
#pragma unroll
      for (int j = 0; j < 4; ++j) {
        int row = nb + crb + j;
        float v = fmaxf(acc[j] + bias, 0.f);
        zb_out[(size_t)row * D + col] = f2bu(v);
        unsigned e = __builtin_amdgcn_cvt_pk_fp8_f32(v, v, 0u, false);
        zf_out[(size_t)row * D + col] = (unsigned char)(e & 0xffu);
      }
    }
  }
}

extern "C" void kernel_launch(void* const* d_in, const int* in_sizes, int n_in,
                              void* d_out, int out_size, void* d_ws, size_t ws_size,
                              hipStream_t stream) {
  const float* x = (const float*)d_in[0];
  const int* ei = (const int*)d_in[1];
  const float* w1[3] = {(const float*)d_in[2], (const float*)d_in[6], (const float*)d_in[10]};
  const float* b1[3] = {(const float*)d_in[3], (const float*)d_in[7], (const float*)d_in[11]};
  const float* w2[3] = {(const float*)d_in[4], (const float*)d_in[8], (const float*)d_in[12]};
  const float* b2[3] = {(const float*)d_in[5], (const float*)d_in[9], (const float*)d_in[13]};
  float* out = (float*)d_out;

  char* wsb = (char*)d_ws;
  size_t off = 0;
  auto alloc = [&](size_t bytes) -> void* {
    void* p = wsb + off;
    off += (bytes + 255) & ~(size_t)255;
    return p;
  };
  unsigned short* zbA = (unsigned short*)alloc((size_t)(NN + 1) * D * 2);
  unsigned short* zbB = (unsigned short*)alloc((size_t)(NN + 1) * D * 2);
  unsigned char* zfA = (unsigned char*)alloc((size_t)(NN + 1) * D);
  unsigned char* zfB = (unsigned char*)alloc((size_t)(NN + 1) * D);
  unsigned short* wt  = (unsigned short*)alloc((size_t)6 * D * D * 2);
  int* fill = (int*)alloc((size_t)NDPAD * 4);
  unsigned short* col_ell = (unsigned short*)alloc((size_t)NDPAD * CAP * 2);

  prep_kernel<<<PREP_BLK, 256, 0, stream>>>(
      (const float4*)x, (uint2*)zbA, (uint2*)zbB, (unsigned*)zfA, (unsigned*)zfB,
      w1[0], w2[0], w1[1], w2[1], w1[2], w2[2], wt, fill);
  csr_kernel<<<(NE / ECHUNK) * 8, 256, 0, stream>>>(ei, fill, col_ell);

  const unsigned short* zin = zbA;
  unsigned short* zout = zbB;
  const unsigned char* fin = zfA;
  unsigned char* fout = zfB;
  for (int l = 0; l < 3; ++l) {
    layer_kernel<<<NN / 16, 512, 0, stream>>>(
        (const uint4*)zin, (const uint2*)fin, fill, col_ell,
        wt + (size_t)(2 * l) * D * D, b1[l],
        wt + (size_t)(2 * l + 1) * D * D, b2[l],
        zout, fout, (l == 2) ? out : nullptr);
    const unsigned short* t = zin; zin = zout; zout = (unsigned short*)t;
    const unsigned char* t2 = fin; fin = fout; fout = (unsigned char*)t2;
  }
}